// Round 2
// baseline (1012.597 us; speedup 1.0000x reference)
//
#include <hip/hip_runtime.h>
#include <hip/hip_bf16.h>

// ---------------- param layout inside ws (floats) ----------------
#define P_W1  0
#define P_AS1 16384
#define P_AD1 16448
#define P_B1  16512
#define P_W2  16576
#define P_AS2 16768
#define P_AD2 16771
#define P_B2  16774

#define NBLK_E 512

typedef __attribute__((ext_vector_type(8))) short short8;
typedef __attribute__((ext_vector_type(8))) unsigned short ushort8v;
typedef __attribute__((ext_vector_type(4))) float floatx4;

// runtime-dtype load helpers
__device__ __forceinline__ float ldf(const void* p, int i, int bf) {
  if (bf) {
    unsigned v = ((unsigned)((const unsigned short*)p)[i]) << 16;
    float f; __builtin_memcpy(&f, &v, 4); return f;
  }
  return ((const float*)p)[i];
}
__device__ __forceinline__ int ldi(const void* p, long i, int i64) {
  return i64 ? ((const int*)p)[2*i] : ((const int*)p)[i];
}
__device__ __forceinline__ unsigned short f2bfbits(float f) {
  __hip_bfloat16 b = __float2bfloat16(f);
  unsigned short u; __builtin_memcpy(&u, &b, 2); return u;
}
__device__ __forceinline__ float bf2f(unsigned short u) {
  unsigned v = ((unsigned)u) << 16;
  float f; __builtin_memcpy(&f, &v, 4); return f;
}

// ---------------- K0: dtype detection + param conversion ----------------
__global__ void k_prep(const void* x, const void* ei,
                       const void* w1, const void* as1, const void* ad1, const void* b1,
                       const void* w2, const void* as2, const void* ad2, const void* b2,
                       int* flags, float* params, unsigned short* w1t) {
  __shared__ int sh[2];
  int tid = threadIdx.x, lane = tid & 63, w = tid >> 6;
  if (w == 0) {
    const unsigned* xw = (const unsigned*)x;
    int hits = 0;
    for (int i = lane; i < 256; i += 64) {
      unsigned b = (xw[i] >> 7) & 0xFF;
      hits += (b >= 96 && b <= 141) ? 1 : 0;
    }
    for (int o = 32; o >= 1; o >>= 1) hits += __shfl_xor(hits, o);
    if (lane == 0) sh[0] = (hits >= 160) ? 1 : 0;
  } else if (w == 1) {
    const unsigned* ew = (const unsigned*)ei;
    int z = 0;
    for (int i = lane; i < 128; i += 64) z += (ew[2*i+1] == 0u) ? 1 : 0;
    for (int o = 32; o >= 1; o >>= 1) z += __shfl_xor(z, o);
    if (lane == 0) sh[1] = (z >= 64) ? 1 : 0;
  }
  __syncthreads();
  int bf = sh[0];
  if (tid == 0) { flags[0] = sh[0]; flags[1] = sh[1]; }
  for (int i = tid; i < 16384; i += blockDim.x) {
    int ch = i >> 8, k = i & 255;
    w1t[i] = f2bfbits(ldf(w1, k * 64 + ch, bf));
  }
  if (!bf) {
    for (int i = tid; i < 16384; i += blockDim.x) params[P_W1 + i] = ldf(w1, i, bf);
  }
  for (int i = tid; i < 64; i += blockDim.x) {
    params[P_AS1 + i] = ldf(as1, i, bf);
    params[P_AD1 + i] = ldf(ad1, i, bf);
    params[P_B1  + i] = ldf(b1,  i, bf);
  }
  for (int i = tid; i < 192; i += blockDim.x) params[P_W2 + i] = ldf(w2, i, bf);
  for (int i = tid; i < 3; i += blockDim.x) {
    params[P_AS2 + i] = ldf(as2, i, bf);
    params[P_AD2 + i] = ldf(ad2, i, bf);
    params[P_B2  + i] = ldf(b2,  i, bf);
  }
}

// ---------------- direct-placement CSR: hist -> scan -> scatter ----------------
// k_hist: global-atomic in-degree histogram (rowcnt is 400KB, L2-resident).
// Reads ONLY the dst half of ei (25.6 MB). Self-loops accounted in k_scan1 (+1/node).
__global__ void k_hist(const void* ei, const int* flags, int* rowcnt, int E0, int chunk) {
  int i64 = flags[1], tid = threadIdx.x;
  int b0 = blockIdx.x * chunk, b1 = min(b0 + chunk, E0);
  for (int e = b0 + tid; e < b1; e += 256) {
    int dst = ldi(ei, (long)E0 + e, i64);
    atomicAdd(&rowcnt[dst], 1);
  }
}

// k_scan1: per-block (1024-elem) exclusive scan of (rowcnt[n]+1) into rowp, block sums out.
__global__ void k_scan1(const int* rowcnt, int* rowp, int* bsum, int N) {
  __shared__ int sh[256];
  int b = blockIdx.x, tid = threadIdx.x;
  int base = b * 1024 + tid * 4;
  int v0 = 0, v1 = 0, v2 = 0, v3 = 0;
  if (base + 0 < N) v0 = rowcnt[base + 0] + 1;
  if (base + 1 < N) v1 = rowcnt[base + 1] + 1;
  if (base + 2 < N) v2 = rowcnt[base + 2] + 1;
  if (base + 3 < N) v3 = rowcnt[base + 3] + 1;
  int t = v0 + v1 + v2 + v3;
  sh[tid] = t;
  __syncthreads();
  for (int ofs = 1; ofs < 256; ofs <<= 1) {
    int u = (tid >= ofs) ? sh[tid - ofs] : 0;
    __syncthreads();
    sh[tid] += u;
    __syncthreads();
  }
  int p = sh[tid] - t;     // exclusive prefix of this thread's chunk
  if (tid == 255) bsum[b] = sh[255];
  if (base + 0 < N) rowp[base + 0] = p; p += v0;
  if (base + 1 < N) rowp[base + 1] = p; p += v1;
  if (base + 2 < N) rowp[base + 2] = p; p += v2;
  if (base + 3 < N) rowp[base + 3] = p;
}

// k_scan2: add block offsets; produce final rowp and a cursor copy for the scatter.
__global__ void k_scan2(const int* bsum, int* rowp, int* cursor, int N, int NBK, int E) {
  __shared__ int off_s;
  int b = blockIdx.x, tid = threadIdx.x;
  if (tid == 0) {
    int o = 0;
    for (int j = 0; j < b; j++) o += bsum[j];
    off_s = o;
  }
  __syncthreads();
  int off = off_s;
  int base = b * 1024 + tid * 4;
#pragma unroll
  for (int j = 0; j < 4; j++) {
    int n = base + j;
    if (n < N) { int r = rowp[n] + off; rowp[n] = r; cursor[n] = r; }
  }
  if (b == NBK - 1 && tid == 0) rowp[N] = E;
}

// k_scatter: one full ei read; place src directly at atomically-claimed slot.
// Order within a row is arbitrary — softmax aggregation is order-insensitive.
__global__ void k_scatter(const void* ei, const int* flags, int* cursor, int* srcs,
                          int E0, int N, int chunk) {
  int i64 = flags[1], tid = threadIdx.x;
  int E = E0 + N;
  int b0 = blockIdx.x * chunk, b1 = min(b0 + chunk, E);
  for (int e = b0 + tid; e < b1; e += 256) {
    int src, dst;
    if (e < E0) { src = ldi(ei, e, i64); dst = ldi(ei, (long)E0 + e, i64); }
    else        { src = e - E0; dst = src; }
    int pos = atomicAdd(&cursor[dst], 1);
    srcs[pos] = src;
  }
}

// ---------------- f32 fallback gemm (per-wave, 4 nodes) ----------------
__device__ __forceinline__ void gemm1_f32(const float* x, const float* params,
                                          unsigned short* h1, float* a_s, float* a_d,
                                          int N, int wave, int lane) {
  int n0 = wave * 4;
  if (n0 >= N) return;
  int nb[4];
#pragma unroll
  for (int j = 0; j < 4; j++) nb[j] = min(n0 + j, N - 1) * 256;
  float acc[4] = {0.f, 0.f, 0.f, 0.f};
  const float* W = params + P_W1;
  for (int k = 0; k < 256; k++) {
    float wv = W[k * 64 + lane];
#pragma unroll
    for (int j = 0; j < 4; j++) acc[j] += x[nb[j] + k] * wv;
  }
  float as1v = params[P_AS1 + lane], ad1v = params[P_AD1 + lane];
#pragma unroll
  for (int j = 0; j < 4; j++) {
    int n = n0 + j;
    if (n >= N) break;
    float hv = acc[j];
    float s = hv * as1v, d = hv * ad1v;
    s += __shfl_xor(s, 1); s += __shfl_xor(s, 2); s += __shfl_xor(s, 4);
    d += __shfl_xor(d, 1); d += __shfl_xor(d, 2); d += __shfl_xor(d, 4);
    h1[(size_t)n * 64 + lane] = f2bfbits(hv);
    if ((lane & 7) == 0) {
      a_s[n * 8 + (lane >> 3)] = s;
      a_d[n * 8 + (lane >> 3)] = d;
    }
  }
}

// ---------------- K1: gemm1, standalone, 32-row tiles (16KB LDS -> higher occupancy) ----------------
__global__ void k_gemm1(const void* x, const unsigned short* w1t, const int* flags,
                        const float* params, unsigned short* h1, float* a_s, float* a_d, int N) {
  __shared__ __align__(16) char smem[16384];
  int tid = threadIdx.x;
  int tile = blockIdx.x;
  int w = tid >> 6, lane = tid & 63;
  if (flags[0]) {
    int row0 = tile << 5;                     // 32 rows per tile
    int l16 = lane & 15, quad = lane >> 4;
    int ch = w * 16 + l16;
    const char* xb = (const char*)x;
    // stage: 32 rows x 512B = 1024 x 16B chunks; 4 per lane.
    // LDS linear dest; global source pre-swizzled (byte ^ ((row&7)<<4)) — both-sides rule.
#pragma unroll
    for (int j = 0; j < 4; j++) {
      int g = w * 256 + j * 64 + lane;        // 16B-chunk id within tile
      int r = g >> 4;                         // local row 0..31
      int p = (g & 15) << 4;                  // byte offset within row
      int gr = row0 + r; if (gr >= N) gr = N - 1;
      const char* src = xb + (size_t)gr * 512 + (size_t)(p ^ ((r & 7) << 4));
      char* dst = smem + w * 4096 + j * 1024 + lane * 16;
      __builtin_amdgcn_global_load_lds((const __attribute__((address_space(1))) unsigned int*)src,
                                       (__attribute__((address_space(3))) unsigned int*)dst,
                                       16, 0, 0);
    }
    // B fragments in registers: full K=256 for this wave's 16 channels (reused 2x)
    short8 bfr[8];
    const unsigned short* wp = w1t + (size_t)ch * 256 + quad * 8;
#pragma unroll
    for (int i = 0; i < 8; i++) bfr[i] = *(const short8*)(wp + i * 32);
    __syncthreads();                          // drains vmcnt(0): staged tile ready
    floatx4 acc[2];
#pragma unroll
    for (int rg = 0; rg < 2; rg++) {
      floatx4 a4 = {0.f, 0.f, 0.f, 0.f};
      int r = rg * 16 + l16;
      const char* arow = smem + r * 512;
      int swz = (r & 7) << 4;
#pragma unroll
      for (int i = 0; i < 8; i++) {
        short8 afr = *(const short8*)(arow + ((quad * 16 + i * 64) ^ swz));
        a4 = __builtin_amdgcn_mfma_f32_16x16x32_bf16(afr, bfr[i], a4, 0, 0, 0);
      }
      acc[rg] = a4;
    }
    __syncthreads();                          // tile reads done; reuse smem as h-tile
    float* ht = (float*)smem;                 // [32][68] f32 (pitch 68 breaks pow2 stride)
#pragma unroll
    for (int rg = 0; rg < 2; rg++)
#pragma unroll
      for (int rr = 0; rr < 4; rr++)
        ht[(rg * 16 + quad * 4 + rr) * 68 + ch] = acc[rg][rr];
    __syncthreads();
    // store pass: thread -> (node, head); 16B-coalesced h1, coalesced 4B a_s/a_d
    int nl = tid >> 3, head = tid & 7;        // 32 nodes x 8 heads = 256 threads
    int n = row0 + nl;
    if (n < N) {
      const float* hr = ht + nl * 68 + head * 8;
      float s = 0.f, d = 0.f;
      ushort8v u;
#pragma unroll
      for (int c = 0; c < 8; c++) {
        float v = hr[c];
        s += v * params[P_AS1 + head * 8 + c];
        d += v * params[P_AD1 + head * 8 + c];
        u[c] = f2bfbits(v);
      }
      *(ushort8v*)(h1 + (size_t)n * 64 + head * 8) = u;
      a_s[n * 8 + head] = s;
      a_d[n * 8 + head] = d;
    }
  } else {
    // f32 fallback: each tile = 32 nodes = 8 wave-tasks of 4 nodes
    for (int k4 = 0; k4 < 2; k4++)
      gemm1_f32((const float*)x, params, h1, a_s, a_d, N, tile * 8 + w * 2 + k4, lane);
  }
}

// ---------------- K5: layer-1 softmax-aggregate + ELU + fused gemm2 (bf16 h1 gathers) ----------------
__global__ void k_agg1(const float* params, const unsigned short* h1, const float* a_s,
                       const float* a_d, const int* rowp, const int* srcs,
                       float4* pk, float* ad2, int N) {
  int n = blockIdx.x * (blockDim.x >> 6) + (threadIdx.x >> 6);
  int lane = threadIdx.x & 63;
  if (n >= N) return;
  int start = rowp[n], end = rowp[n + 1];
  int h = lane & 7, es = lane >> 3;
  float adh = a_d[n * 8 + h];
  float m = -1e30f;
  for (int i = start + es; i < end; i += 8) {
    float e = a_s[srcs[i] * 8 + h] + adh;
    e = e > 0.f ? e : 0.2f * e;
    m = fmaxf(m, e);
  }
  m = fmaxf(m, __shfl_xor(m, 8));
  m = fmaxf(m, __shfl_xor(m, 16));
  m = fmaxf(m, __shfl_xor(m, 32));
  float acc[8] = {0.f,0.f,0.f,0.f,0.f,0.f,0.f,0.f};
  float ssum = 0.f;
  for (int i = start + es; i < end; i += 8) {
    int s = srcs[i];
    float e = a_s[s * 8 + h] + adh;
    e = e > 0.f ? e : 0.2f * e;
    float ex = __expf(e - m);
    ssum += ex;
    ushort8v u = *(const ushort8v*)(h1 + (size_t)s * 64 + h * 8);  // 16B gather
#pragma unroll
    for (int c = 0; c < 8; c++) acc[c] += ex * bf2f(u[c]);
  }
#pragma unroll
  for (int msk = 8; msk <= 32; msk <<= 1) {
    ssum += __shfl_xor(ssum, msk);
#pragma unroll
    for (int c = 0; c < 8; c++) acc[c] += __shfl_xor(acc[c], msk);
  }
  if (es == 0) {   // lanes 0..7, lane == h
    float inv = 1.f / (ssum + 1e-16f);
    float pj0 = 0.f, pj1 = 0.f, pj2 = 0.f;
#pragma unroll
    for (int c = 0; c < 8; c++) {
      float v = acc[c] * inv + params[P_B1 + h * 8 + c];
      v = v > 0.f ? v : (__expf(v) - 1.f);   // ELU
      const float* w2r = params + P_W2 + (h * 8 + c) * 3;
      pj0 += v * w2r[0]; pj1 += v * w2r[1]; pj2 += v * w2r[2];
    }
    pj0 += __shfl_xor(pj0, 1); pj1 += __shfl_xor(pj1, 1); pj2 += __shfl_xor(pj2, 1);
    pj0 += __shfl_xor(pj0, 2); pj1 += __shfl_xor(pj1, 2); pj2 += __shfl_xor(pj2, 2);
    pj0 += __shfl_xor(pj0, 4); pj1 += __shfl_xor(pj1, 4); pj2 += __shfl_xor(pj2, 4);
    if (h == 0) {
      float as2 = pj0*params[P_AS2+0] + pj1*params[P_AS2+1] + pj2*params[P_AS2+2];
      float ad2v = pj0*params[P_AD2+0] + pj1*params[P_AD2+1] + pj2*params[P_AD2+2];
      pk[n] = make_float4(pj0, pj1, pj2, as2);
      ad2[n] = ad2v;
    }
  }
}

// ---------------- K7: layer-2 softmax-aggregate + bias -> d_out ----------------
__global__ void k_agg2(const float* params, const float4* pk, const float* ad2,
                       const int* rowp, const int* srcs, void* out, const int* flags, int N) {
  int wid = blockIdx.x * (blockDim.x >> 6) + (threadIdx.x >> 6);
  int lane = threadIdx.x & 63;
  int g = lane >> 4, t = lane & 15;
  int n = wid * 4 + g;
  if (n >= N) return;
  int start = rowp[n], end = rowp[n + 1];
  float ad = ad2[n];
  float m = -1e30f;
  for (int i = start + t; i < end; i += 16) {
    float e = pk[srcs[i]].w + ad;
    e = e > 0.f ? e : 0.2f * e;
    m = fmaxf(m, e);
  }
#pragma unroll
  for (int msk = 1; msk <= 8; msk <<= 1) m = fmaxf(m, __shfl_xor(m, msk));
  float ssum = 0.f, c0 = 0.f, c1 = 0.f, c2 = 0.f;
  for (int i = start + t; i < end; i += 16) {
    float4 v = pk[srcs[i]];
    float e = v.w + ad;
    e = e > 0.f ? e : 0.2f * e;
    float ex = __expf(e - m);
    ssum += ex;
    c0 += ex * v.x; c1 += ex * v.y; c2 += ex * v.z;
  }
#pragma unroll
  for (int msk = 1; msk <= 8; msk <<= 1) {
    ssum += __shfl_xor(ssum, msk);
    c0 += __shfl_xor(c0, msk); c1 += __shfl_xor(c1, msk); c2 += __shfl_xor(c2, msk);
  }
  if (t == 0) {
    float inv = 1.f / (ssum + 1e-16f);
    float o0 = c0 * inv + params[P_B2+0];
    float o1 = c1 * inv + params[P_B2+1];
    float o2 = c2 * inv + params[P_B2+2];
    if (flags[0]) {
      __hip_bfloat16* ob = (__hip_bfloat16*)out;
      ob[n*3+0] = __float2bfloat16(o0);
      ob[n*3+1] = __float2bfloat16(o1);
      ob[n*3+2] = __float2bfloat16(o2);
    } else {
      float* of = (float*)out;
      of[n*3+0] = o0; of[n*3+1] = o1; of[n*3+2] = o2;
    }
  }
}

// ---------------- launch ----------------
extern "C" void kernel_launch(void* const* d_in, const int* in_sizes, int n_in,
                              void* d_out, int out_size, void* d_ws, size_t ws_size,
                              hipStream_t stream) {
  const void* x  = d_in[0];
  const void* ei = d_in[1];
  int N  = in_sizes[0] / 256;   // 100000
  int E0 = in_sizes[1] / 2;     // 3200000
  int E  = E0 + N;
  int NBK = (N + 1023) >> 10;   // scan blocks (1024 elems each)
  int chunk0 = (E0 + NBLK_E - 1) / NBLK_E;
  int chunkE = (E  + NBLK_E - 1) / NBLK_E;
  int ntile = (N + 31) >> 5;    // 32-row gemm1 tiles

  char* w = (char*)d_ws;
  size_t off = 0;
  auto alloc = [&](size_t bytes) -> char* {
    char* p = w + off;
    off += (bytes + 255) & ~(size_t)255;
    return p;
  };
  int*            flags  = (int*)           alloc(256);
  float*          params = (float*)         alloc(17408 * 4);
  unsigned short* w1t    = (unsigned short*)alloc(16384 * 2);
  unsigned short* h1     = (unsigned short*)alloc((size_t)N * 64 * 2);
  float*          a_s1   = (float*)         alloc((size_t)N * 8 * 4);
  float*          a_d1   = (float*)         alloc((size_t)N * 8 * 4);
  float4*         pk     = (float4*)        alloc((size_t)N * 16);
  float*          ad2    = (float*)         alloc((size_t)N * 4);
  int*            rowcnt = (int*)           alloc((size_t)N * 4);
  int*            rowp   = (int*)           alloc((size_t)(N + 1) * 4);
  int*            cursor = (int*)           alloc((size_t)N * 4);
  int*            bsum   = (int*)           alloc((size_t)NBK * 4);
  int*            srcs   = (int*)           alloc((size_t)E * 4);
  (void)ws_size; (void)n_in; (void)out_size;

  hipMemsetAsync(rowcnt, 0, (size_t)N * 4, stream);
  k_prep<<<1, 256, 0, stream>>>(x, ei, d_in[2], d_in[3], d_in[4], d_in[5],
                                d_in[6], d_in[7], d_in[8], d_in[9], flags, params, w1t);
  // gemm1 first: independent of the CSR chain
  k_gemm1<<<dim3(ntile), 256, 0, stream>>>(x, w1t, flags, params, h1, a_s1, a_d1, N);
  // direct-placement CSR (no pairs, no bucket sort)
  k_hist<<<dim3(NBLK_E), 256, 0, stream>>>(ei, flags, rowcnt, E0, chunk0);
  k_scan1<<<dim3(NBK), 256, 0, stream>>>(rowcnt, rowp, bsum, N);
  k_scan2<<<dim3(NBK), 256, 0, stream>>>(bsum, rowp, cursor, N, NBK, E);
  k_scatter<<<dim3(NBLK_E), 256, 0, stream>>>(ei, flags, cursor, srcs, E0, N, chunkE);
  k_agg1<<<dim3((N + 3) / 4), 256, 0, stream>>>(params, h1, a_s1, a_d1, rowp, srcs, pk, ad2, N);
  k_agg2<<<dim3((N + 15) / 16), 256, 0, stream>>>(params, pk, ad2, rowp, srcs, d_out, flags, N);
}

// Round 3
// 682.939 us; speedup vs baseline: 1.4827x; 1.4827x over previous
//
#include <hip/hip_runtime.h>
#include <hip/hip_bf16.h>

// ---------------- param layout inside ws (floats) ----------------
#define P_W1  0
#define P_AS1 16384
#define P_AD1 16448
#define P_B1  16512
#define P_W2  16576
#define P_AS2 16768
#define P_AD2 16771
#define P_B2  16774

#define NBLK_CSR 512
#define G1GRID   1024

typedef __attribute__((ext_vector_type(8))) short short8;
typedef __attribute__((ext_vector_type(8))) unsigned short ushort8v;
typedef __attribute__((ext_vector_type(4))) float floatx4;

// runtime-dtype load helpers
__device__ __forceinline__ float ldf(const void* p, int i, int bf) {
  if (bf) {
    unsigned v = ((unsigned)((const unsigned short*)p)[i]) << 16;
    float f; __builtin_memcpy(&f, &v, 4); return f;
  }
  return ((const float*)p)[i];
}
__device__ __forceinline__ int ldi(const void* p, long i, int i64) {
  return i64 ? ((const int*)p)[2*i] : ((const int*)p)[i];
}
__device__ __forceinline__ unsigned short f2bfbits(float f) {
  __hip_bfloat16 b = __float2bfloat16(f);
  unsigned short u; __builtin_memcpy(&u, &b, 2); return u;
}
__device__ __forceinline__ float bf2f(unsigned short u) {
  unsigned v = ((unsigned)u) << 16;
  float f; __builtin_memcpy(&f, &v, 4); return f;
}

// lgkm-only barrier: does NOT drain vmcnt (keeps global_load_lds prefetch in flight).
// sched_barrier(0) pins LDS ops on both sides (rule #18).
__device__ __forceinline__ void bar_lgkm() {
  __builtin_amdgcn_sched_barrier(0);
  asm volatile("s_waitcnt lgkmcnt(0)" ::: "memory");
  __builtin_amdgcn_s_barrier();
  __builtin_amdgcn_sched_barrier(0);
}

// ---------------- K0: dtype detection + param conversion ----------------
__global__ void k_prep(const void* x, const void* ei,
                       const void* w1, const void* as1, const void* ad1, const void* b1,
                       const void* w2, const void* as2, const void* ad2, const void* b2,
                       int* flags, float* params, unsigned short* w1t) {
  __shared__ int sh[2];
  int tid = threadIdx.x, lane = tid & 63, w = tid >> 6;
  if (w == 0) {
    const unsigned* xw = (const unsigned*)x;
    int hits = 0;
    for (int i = lane; i < 256; i += 64) {
      unsigned b = (xw[i] >> 7) & 0xFF;
      hits += (b >= 96 && b <= 141) ? 1 : 0;
    }
    for (int o = 32; o >= 1; o >>= 1) hits += __shfl_xor(hits, o);
    if (lane == 0) sh[0] = (hits >= 160) ? 1 : 0;
  } else if (w == 1) {
    const unsigned* ew = (const unsigned*)ei;
    int z = 0;
    for (int i = lane; i < 128; i += 64) z += (ew[2*i+1] == 0u) ? 1 : 0;
    for (int o = 32; o >= 1; o >>= 1) z += __shfl_xor(z, o);
    if (lane == 0) sh[1] = (z >= 64) ? 1 : 0;
  }
  __syncthreads();
  int bf = sh[0];
  if (tid == 0) { flags[0] = sh[0]; flags[1] = sh[1]; }
  for (int i = tid; i < 16384; i += blockDim.x) {
    int ch = i >> 8, k = i & 255;
    w1t[i] = f2bfbits(ldf(w1, k * 64 + ch, bf));
  }
  if (!bf) {
    for (int i = tid; i < 16384; i += blockDim.x) params[P_W1 + i] = ldf(w1, i, bf);
  }
  for (int i = tid; i < 64; i += blockDim.x) {
    params[P_AS1 + i] = ldf(as1, i, bf);
    params[P_AD1 + i] = ldf(ad1, i, bf);
    params[P_B1  + i] = ldf(b1,  i, bf);
  }
  for (int i = tid; i < 192; i += blockDim.x) params[P_W2 + i] = ldf(w2, i, bf);
  for (int i = tid; i < 3; i += blockDim.x) {
    params[P_AS2 + i] = ldf(as2, i, bf);
    params[P_AD2 + i] = ldf(ad2, i, bf);
    params[P_B2  + i] = ldf(b2,  i, bf);
  }
}

// ---------------- bucketed CSR chain (R0-proven: locality-preserving scatter) ----------------
__global__ void k_bcount(const void* ei, const int* flags, int* gcnt, int* brsv,
                         int E0, int N, int NB, int chunk) {
  __shared__ int h[256];
  int tid = threadIdx.x;
  int i64 = flags[1];
  for (int j = tid; j < NB; j += 256) h[j] = 0;
  __syncthreads();
  int E = E0 + N;
  int b0 = blockIdx.x * chunk, b1 = min(b0 + chunk, E);
  for (int e = b0 + tid; e < b1; e += 256) {
    int dst = (e < E0) ? ldi(ei, (long)E0 + e, i64) : (e - E0);
    atomicAdd(&h[dst >> 9], 1);
  }
  __syncthreads();
  for (int j = tid; j < NB; j += 256)
    brsv[blockIdx.x * NB + j] = atomicAdd(&gcnt[j], h[j]);
}

__global__ void k_bbase(const int* gcnt, int* bbase, int NB) {
  __shared__ int sh[256];
  int tid = threadIdx.x;
  sh[tid] = (tid < NB) ? gcnt[tid] : 0;
  __syncthreads();
  int own = sh[tid];
  for (int ofs = 1; ofs < 256; ofs <<= 1) {
    int v = (tid >= ofs) ? sh[tid - ofs] : 0;
    __syncthreads();
    sh[tid] += v;
    __syncthreads();
  }
  if (tid < NB) bbase[tid] = sh[tid] - own;
  if (tid == NB - 1) bbase[NB] = sh[tid];
}

__global__ void k_bscatter(const void* ei, const int* flags, const int* bbase,
                           const int* brsv, unsigned* pairs, int E0, int N, int NB, int chunk) {
  __shared__ int base_s[256];
  __shared__ int rnk[256];
  int i64 = flags[1], tid = threadIdx.x;
  for (int j = tid; j < NB; j += 256) {
    base_s[j] = bbase[j] + brsv[blockIdx.x * NB + j];
    rnk[j] = 0;
  }
  __syncthreads();
  int E = E0 + N;
  int b0 = blockIdx.x * chunk, b1 = min(b0 + chunk, E);
  for (int e = b0 + tid; e < b1; e += 256) {
    int src, dst;
    if (e < E0) { src = ldi(ei, e, i64); dst = ldi(ei, (long)E0 + e, i64); }
    else        { src = e - E0; dst = src; }
    int bkt = dst >> 9;
    int r = atomicAdd(&rnk[bkt], 1);
    pairs[base_s[bkt] + r] = ((unsigned)src << 9) | (unsigned)(dst & 511);
  }
}

__global__ void k_bsort(const unsigned* pairs, const int* bbase, int* rowp,
                        int* srcs, int N, int NB, int E) {
  __shared__ int h0[512], sc[512], rk[512];
  int b = blockIdx.x, tid = threadIdx.x;
  int s0 = bbase[b], s1 = bbase[b + 1], L = s1 - s0;
  for (int j = tid; j < 512; j += 256) { h0[j] = 0; rk[j] = 0; }
  __syncthreads();
  for (int i = tid; i < L; i += 256) atomicAdd(&h0[pairs[s0 + i] & 511], 1);
  __syncthreads();
  for (int j = tid; j < 512; j += 256) sc[j] = h0[j];
  __syncthreads();
  for (int ofs = 1; ofs < 512; ofs <<= 1) {
    int j0 = tid, j1 = tid + 256;
    int v0 = (j0 >= ofs) ? sc[j0 - ofs] : 0;
    int v1 = (j1 >= ofs) ? sc[j1 - ofs] : 0;
    __syncthreads();
    sc[j0] += v0; sc[j1] += v1;
    __syncthreads();
  }
  for (int j = tid; j < 512; j += 256) {
    int off = sc[j] - h0[j];
    int node = (b << 9) + j;
    if (node < N) rowp[node] = s0 + off;
    sc[j] = off;
  }
  if (b == 0 && tid == 0) rowp[N] = E;
  __syncthreads();
  for (int i = tid; i < L; i += 256) {
    unsigned p = pairs[s0 + i];
    int j = p & 511;
    int r = atomicAdd(&rk[j], 1);
    srcs[s0 + sc[j] + r] = (int)(p >> 9);
  }
}

// ---------------- f32 fallback gemm (per-wave, 4 nodes) ----------------
__device__ __forceinline__ void gemm1_f32(const float* x, const float* params,
                                          unsigned short* h1, float* a_s, float* a_d,
                                          int N, int wave, int lane) {
  int n0 = wave * 4;
  if (n0 >= N) return;
  int nb[4];
#pragma unroll
  for (int j = 0; j < 4; j++) nb[j] = min(n0 + j, N - 1) * 256;
  float acc[4] = {0.f, 0.f, 0.f, 0.f};
  const float* W = params + P_W1;
  for (int k = 0; k < 256; k++) {
    float wv = W[k * 64 + lane];
#pragma unroll
    for (int j = 0; j < 4; j++) acc[j] += x[nb[j] + k] * wv;
  }
  float as1v = params[P_AS1 + lane], ad1v = params[P_AD1 + lane];
#pragma unroll
  for (int j = 0; j < 4; j++) {
    int n = n0 + j;
    if (n >= N) break;
    float hv = acc[j];
    float s = hv * as1v, d = hv * ad1v;
    s += __shfl_xor(s, 1); s += __shfl_xor(s, 2); s += __shfl_xor(s, 4);
    d += __shfl_xor(d, 1); d += __shfl_xor(d, 2); d += __shfl_xor(d, 4);
    h1[(size_t)n * 64 + lane] = f2bfbits(hv);
    if ((lane & 7) == 0) {
      a_s[n * 8 + (lane >> 3)] = s;
      a_d[n * 8 + (lane >> 3)] = d;
    }
  }
}

// ---------------- K1: persistent double-buffered gemm1 ----------------
// 1024 grid-stride blocks, 32-row tiles, 2x16KB LDS buffers. stage(t+G) issued right
// after the per-tile __syncthreads (the only vmcnt(0) drain) so its 16 global_load_lds
// stay in flight across the whole MFMA/transpose/store phase of tile t. Mid-tile
// barriers are lgkm-only (never drain the prefetch).
__global__ void k_gemm1(const void* x, const unsigned short* w1t, const int* flags,
                        const float* params, unsigned short* h1, float* a_s, float* a_d, int N) {
  __shared__ __align__(16) char smem[32768];
  int tid = threadIdx.x;
  int w = tid >> 6, lane = tid & 63;
  if (flags[0]) {
    int NT = (N + 31) >> 5;
    int l16 = lane & 15, quad = lane >> 4;
    int ch = w * 16 + l16;
    const char* xb = (const char*)x;

    // stage tile t into buffer bsel: 32 rows x 512B; linear LDS dest, XOR-swizzled source
    // (chunk c of row r lands at LDS slot c^(r&7)) — R1-proven formula.
    auto stage = [&](int t, int bsel) {
      int row0 = t << 5;
      char* buf = smem + bsel * 16384;
#pragma unroll
      for (int jj = 0; jj < 4; jj++) {
        int g = w * 256 + jj * 64 + lane;     // 16B-chunk id, 32 chunks/row
        int r = g >> 5;                       // local row 0..31
        int c = g & 31;                       // chunk within row
        int gr = row0 + r; if (gr >= N) gr = N - 1;
        const char* src = xb + (size_t)gr * 512 + (size_t)((c << 4) ^ ((r & 7) << 4));
        char* dst = buf + g * 16;
        __builtin_amdgcn_global_load_lds((const __attribute__((address_space(1))) unsigned int*)src,
                                         (__attribute__((address_space(3))) unsigned int*)dst,
                                         16, 0, 0);
      }
    };

    // B fragments in registers once per block (w1t is L2-resident)
    short8 bfr[8];
    const unsigned short* wp = w1t + (size_t)ch * 256 + quad * 8;
#pragma unroll
    for (int i = 0; i < 8; i++) bfr[i] = *(const short8*)(wp + i * 32);
    __builtin_amdgcn_sched_barrier(0);

    int t0 = blockIdx.x;
    if (t0 < NT) stage(t0, 0);
    int cur = 0;
    for (int t = t0; t < NT; t += G1GRID) {
      __syncthreads();                        // B1: buf[cur] staged (vmcnt0), all LDS retired
      if (t + G1GRID < NT) stage(t + G1GRID, cur ^ 1);   // prefetch next tile
      int row0 = t << 5;
      const char* buf = smem + cur * 16384;
      floatx4 acc[2];
#pragma unroll
      for (int rg = 0; rg < 2; rg++) {
        floatx4 a4 = {0.f, 0.f, 0.f, 0.f};
        int r = rg * 16 + l16;
        const char* arow = buf + r * 512;
        int swz = (r & 7) << 4;
#pragma unroll
        for (int i = 0; i < 8; i++) {
          short8 afr = *(const short8*)(arow + ((quad * 16 + i * 64) ^ swz));
          a4 = __builtin_amdgcn_mfma_f32_16x16x32_bf16(afr, bfr[i], a4, 0, 0, 0);
        }
        acc[rg] = a4;
      }
      bar_lgkm();                             // B2: MFMA ds_reads done -> reuse buf[cur] as ht
      float* ht = (float*)(smem + cur * 16384);  // [32][67] f32 (pitch 67: conflict-light)
#pragma unroll
      for (int rg = 0; rg < 2; rg++)
#pragma unroll
        for (int rr = 0; rr < 4; rr++)
          ht[(rg * 16 + quad * 4 + rr) * 67 + ch] = acc[rg][rr];
      bar_lgkm();                             // B3: ht written -> readable
      int nl = tid >> 3, head = tid & 7;      // 32 nodes x 8 heads
      int n = row0 + nl;
      if (n < N) {
        const float* hr = ht + nl * 67 + head * 8;
        float s = 0.f, d = 0.f;
        ushort8v u;
#pragma unroll
        for (int c = 0; c < 8; c++) {
          float v = hr[c];
          s += v * params[P_AS1 + head * 8 + c];
          d += v * params[P_AD1 + head * 8 + c];
          u[c] = f2bfbits(v);
        }
        *(ushort8v*)(h1 + (size_t)n * 64 + head * 8) = u;
        a_s[n * 8 + head] = s;
        a_d[n * 8 + head] = d;
      }
      cur ^= 1;
      // next B1's lgkmcnt(0)+barrier retires these ht reads before buf[cur^1] is restaged
    }
  } else {
    int NW = (N + 3) >> 2;
    for (int task = blockIdx.x * 4 + w; task < NW; task += G1GRID * 4)
      gemm1_f32((const float*)x, params, h1, a_s, a_d, N, task, lane);
  }
}

// ---------------- K5: layer-1 softmax-aggregate + ELU + fused gemm2 (bf16 h1 gathers) ----------------
__global__ void k_agg1(const float* params, const unsigned short* h1, const float* a_s,
                       const float* a_d, const int* rowp, const int* srcs,
                       float4* pk, float* ad2, int N) {
  int n = blockIdx.x * (blockDim.x >> 6) + (threadIdx.x >> 6);
  int lane = threadIdx.x & 63;
  if (n >= N) return;
  int start = rowp[n], end = rowp[n + 1];
  int h = lane & 7, es = lane >> 3;
  float adh = a_d[n * 8 + h];
  float m = -1e30f;
  for (int i = start + es; i < end; i += 8) {
    float e = a_s[srcs[i] * 8 + h] + adh;
    e = e > 0.f ? e : 0.2f * e;
    m = fmaxf(m, e);
  }
  m = fmaxf(m, __shfl_xor(m, 8));
  m = fmaxf(m, __shfl_xor(m, 16));
  m = fmaxf(m, __shfl_xor(m, 32));
  float acc[8] = {0.f,0.f,0.f,0.f,0.f,0.f,0.f,0.f};
  float ssum = 0.f;
  for (int i = start + es; i < end; i += 8) {
    int s = srcs[i];
    float e = a_s[s * 8 + h] + adh;
    e = e > 0.f ? e : 0.2f * e;
    float ex = __expf(e - m);
    ssum += ex;
    ushort8v u = *(const ushort8v*)(h1 + (size_t)s * 64 + h * 8);  // 16B gather
#pragma unroll
    for (int c = 0; c < 8; c++) acc[c] += ex * bf2f(u[c]);
  }
#pragma unroll
  for (int msk = 8; msk <= 32; msk <<= 1) {
    ssum += __shfl_xor(ssum, msk);
#pragma unroll
    for (int c = 0; c < 8; c++) acc[c] += __shfl_xor(acc[c], msk);
  }
  if (es == 0) {   // lanes 0..7, lane == h
    float inv = 1.f / (ssum + 1e-16f);
    float pj0 = 0.f, pj1 = 0.f, pj2 = 0.f;
#pragma unroll
    for (int c = 0; c < 8; c++) {
      float v = acc[c] * inv + params[P_B1 + h * 8 + c];
      v = v > 0.f ? v : (__expf(v) - 1.f);   // ELU
      const float* w2r = params + P_W2 + (h * 8 + c) * 3;
      pj0 += v * w2r[0]; pj1 += v * w2r[1]; pj2 += v * w2r[2];
    }
    pj0 += __shfl_xor(pj0, 1); pj1 += __shfl_xor(pj1, 1); pj2 += __shfl_xor(pj2, 1);
    pj0 += __shfl_xor(pj0, 2); pj1 += __shfl_xor(pj1, 2); pj2 += __shfl_xor(pj2, 2);
    pj0 += __shfl_xor(pj0, 4); pj1 += __shfl_xor(pj1, 4); pj2 += __shfl_xor(pj2, 4);
    if (h == 0) {
      float as2 = pj0*params[P_AS2+0] + pj1*params[P_AS2+1] + pj2*params[P_AS2+2];
      float ad2v = pj0*params[P_AD2+0] + pj1*params[P_AD2+1] + pj2*params[P_AD2+2];
      pk[n] = make_float4(pj0, pj1, pj2, as2);
      ad2[n] = ad2v;
    }
  }
}

// ---------------- K7: layer-2 softmax-aggregate + bias -> d_out ----------------
__global__ void k_agg2(const float* params, const float4* pk, const float* ad2,
                       const int* rowp, const int* srcs, void* out, const int* flags, int N) {
  int wid = blockIdx.x * (blockDim.x >> 6) + (threadIdx.x >> 6);
  int lane = threadIdx.x & 63;
  int g = lane >> 4, t = lane & 15;
  int n = wid * 4 + g;
  if (n >= N) return;
  int start = rowp[n], end = rowp[n + 1];
  float ad = ad2[n];
  float m = -1e30f;
  for (int i = start + t; i < end; i += 16) {
    float e = pk[srcs[i]].w + ad;
    e = e > 0.f ? e : 0.2f * e;
    m = fmaxf(m, e);
  }
#pragma unroll
  for (int msk = 1; msk <= 8; msk <<= 1) m = fmaxf(m, __shfl_xor(m, msk));
  float ssum = 0.f, c0 = 0.f, c1 = 0.f, c2 = 0.f;
  for (int i = start + t; i < end; i += 16) {
    float4 v = pk[srcs[i]];
    float e = v.w + ad;
    e = e > 0.f ? e : 0.2f * e;
    float ex = __expf(e - m);
    ssum += ex;
    c0 += ex * v.x; c1 += ex * v.y; c2 += ex * v.z;
  }
#pragma unroll
  for (int msk = 1; msk <= 8; msk <<= 1) {
    ssum += __shfl_xor(ssum, msk);
    c0 += __shfl_xor(c0, msk); c1 += __shfl_xor(c1, msk); c2 += __shfl_xor(c2, msk);
  }
  if (t == 0) {
    float inv = 1.f / (ssum + 1e-16f);
    float o0 = c0 * inv + params[P_B2+0];
    float o1 = c1 * inv + params[P_B2+1];
    float o2 = c2 * inv + params[P_B2+2];
    if (flags[0]) {
      __hip_bfloat16* ob = (__hip_bfloat16*)out;
      ob[n*3+0] = __float2bfloat16(o0);
      ob[n*3+1] = __float2bfloat16(o1);
      ob[n*3+2] = __float2bfloat16(o2);
    } else {
      float* of = (float*)out;
      of[n*3+0] = o0; of[n*3+1] = o1; of[n*3+2] = o2;
    }
  }
}

// ---------------- launch ----------------
extern "C" void kernel_launch(void* const* d_in, const int* in_sizes, int n_in,
                              void* d_out, int out_size, void* d_ws, size_t ws_size,
                              hipStream_t stream) {
  const void* x  = d_in[0];
  const void* ei = d_in[1];
  int N  = in_sizes[0] / 256;   // 100000
  int E0 = in_sizes[1] / 2;     // 3200000
  int E  = E0 + N;
  int NB = (N + 511) >> 9;      // 196 buckets (dst >> 9)
  int chunk = (E + NBLK_CSR - 1) / NBLK_CSR;

  char* w = (char*)d_ws;
  size_t off = 0;
  auto alloc = [&](size_t bytes) -> char* {
    char* p = w + off;
    off += (bytes + 255) & ~(size_t)255;
    return p;
  };
  int*            flags  = (int*)           alloc(256);
  float*          params = (float*)         alloc(17408 * 4);
  unsigned short* w1t    = (unsigned short*)alloc(16384 * 2);
  unsigned short* h1     = (unsigned short*)alloc((size_t)N * 64 * 2);
  float*          a_s1   = (float*)         alloc((size_t)N * 8 * 4);
  float*          a_d1   = (float*)         alloc((size_t)N * 8 * 4);
  float4*         pk     = (float4*)        alloc((size_t)N * 16);
  float*          ad2    = (float*)         alloc((size_t)N * 4);
  int*            gcnt   = (int*)           alloc(256 * 4);
  int*            bbase  = (int*)           alloc(257 * 4);
  int*            brsv   = (int*)           alloc((size_t)NBLK_CSR * NB * 4);
  int*            rowp   = (int*)           alloc((size_t)(N + 1) * 4);
  unsigned*       pairs  = (unsigned*)      alloc((size_t)E * 4);
  int*            srcs   = (int*)           alloc((size_t)E * 4);
  (void)ws_size; (void)n_in; (void)out_size;

  hipMemsetAsync(gcnt, 0, 256 * 4, stream);
  k_prep<<<1, 256, 0, stream>>>(x, ei, d_in[2], d_in[3], d_in[4], d_in[5],
                                d_in[6], d_in[7], d_in[8], d_in[9], flags, params, w1t);
  // persistent gemm1 (only needs k_prep)
  k_gemm1<<<dim3(G1GRID), 256, 0, stream>>>(x, w1t, flags, params, h1, a_s1, a_d1, N);
  // bucketed CSR (locality-preserving scatter, R0-proven)
  k_bcount<<<dim3(NBLK_CSR), 256, 0, stream>>>(ei, flags, gcnt, brsv, E0, N, NB, chunk);
  k_bbase<<<1, 256, 0, stream>>>(gcnt, bbase, NB);
  k_bscatter<<<dim3(NBLK_CSR), 256, 0, stream>>>(ei, flags, bbase, brsv, pairs, E0, N, NB, chunk);
  k_bsort<<<dim3(NB), 256, 0, stream>>>(pairs, bbase, rowp, srcs, N, NB, E);
  k_agg1<<<dim3((N + 3) / 4), 256, 0, stream>>>(params, h1, a_s1, a_d1, rowp, srcs, pk, ad2, N);
  k_agg2<<<dim3((N + 15) / 16), 256, 0, stream>>>(params, pk, ad2, rowp, srcs, d_out, flags, N);
}

// Round 5
// 658.378 us; speedup vs baseline: 1.5380x; 1.0373x over previous
//
#include <hip/hip_runtime.h>
#include <hip/hip_bf16.h>

// ---------------- param layout inside ws (floats) ----------------
#define P_W1  0
#define P_AS1 16384
#define P_AD1 16448
#define P_B1  16512
#define P_W2  16576
#define P_AS2 16768
#define P_AD2 16771
#define P_B2  16774

#define NBLK_CSR 512
#define G1GRID   1024

typedef __attribute__((ext_vector_type(8))) short short8;
typedef __attribute__((ext_vector_type(8))) unsigned short ushort8v;
typedef __attribute__((ext_vector_type(4))) float floatx4;

// runtime-dtype load helpers
__device__ __forceinline__ float ldf(const void* p, int i, int bf) {
  if (bf) {
    unsigned v = ((unsigned)((const unsigned short*)p)[i]) << 16;
    float f; __builtin_memcpy(&f, &v, 4); return f;
  }
  return ((const float*)p)[i];
}
__device__ __forceinline__ int ldi(const void* p, long i, int i64) {
  return i64 ? ((const int*)p)[2*i] : ((const int*)p)[i];
}
__device__ __forceinline__ unsigned short f2bfbits(float f) {
  __hip_bfloat16 b = __float2bfloat16(f);
  unsigned short u; __builtin_memcpy(&u, &b, 2); return u;
}
__device__ __forceinline__ float bf2f(unsigned short u) {
  unsigned v = ((unsigned)u) << 16;
  float f; __builtin_memcpy(&f, &v, 4); return f;
}

// lgkm-only barrier: does NOT drain vmcnt (keeps global_load_lds prefetch in flight).
__device__ __forceinline__ void bar_lgkm() {
  __builtin_amdgcn_sched_barrier(0);
  asm volatile("s_waitcnt lgkmcnt(0)" ::: "memory");
  __builtin_amdgcn_s_barrier();
  __builtin_amdgcn_sched_barrier(0);
}

// ---------------- K0: dtype detection + param conversion ----------------
__global__ void k_prep(const void* x, const void* ei,
                       const void* w1, const void* as1, const void* ad1, const void* b1,
                       const void* w2, const void* as2, const void* ad2, const void* b2,
                       int* flags, float* params, unsigned short* w1t) {
  __shared__ int sh[2];
  int tid = threadIdx.x, lane = tid & 63, w = tid >> 6;
  if (w == 0) {
    const unsigned* xw = (const unsigned*)x;
    int hits = 0;
    for (int i = lane; i < 256; i += 64) {
      unsigned b = (xw[i] >> 7) & 0xFF;
      hits += (b >= 96 && b <= 141) ? 1 : 0;
    }
    for (int o = 32; o >= 1; o >>= 1) hits += __shfl_xor(hits, o);
    if (lane == 0) sh[0] = (hits >= 160) ? 1 : 0;
  } else if (w == 1) {
    const unsigned* ew = (const unsigned*)ei;
    int z = 0;
    for (int i = lane; i < 128; i += 64) z += (ew[2*i+1] == 0u) ? 1 : 0;
    for (int o = 32; o >= 1; o >>= 1) z += __shfl_xor(z, o);
    if (lane == 0) sh[1] = (z >= 64) ? 1 : 0;
  }
  __syncthreads();
  int bf = sh[0];
  if (tid == 0) { flags[0] = sh[0]; flags[1] = sh[1]; }
  for (int i = tid; i < 16384; i += blockDim.x) {
    int ch = i >> 8, k = i & 255;
    w1t[i] = f2bfbits(ldf(w1, k * 64 + ch, bf));
  }
  if (!bf) {
    for (int i = tid; i < 16384; i += blockDim.x) params[P_W1 + i] = ldf(w1, i, bf);
  }
  for (int i = tid; i < 64; i += blockDim.x) {
    params[P_AS1 + i] = ldf(as1, i, bf);
    params[P_AD1 + i] = ldf(ad1, i, bf);
    params[P_B1  + i] = ldf(b1,  i, bf);
  }
  for (int i = tid; i < 192; i += blockDim.x) params[P_W2 + i] = ldf(w2, i, bf);
  for (int i = tid; i < 3; i += blockDim.x) {
    params[P_AS2 + i] = ldf(as2, i, bf);
    params[P_AD2 + i] = ldf(ad2, i, bf);
    params[P_B2  + i] = ldf(b2,  i, bf);
  }
}

// ---------------- bucketed CSR chain (vectorized ei reads: 2 edges/lane) ----------------
__global__ void k_bcount(const void* ei, const int* flags, int* gcnt, int* brsv,
                         int E0, int N, int NB, int chunk) {
  __shared__ int h[256];
  int tid = threadIdx.x;
  int i64 = flags[1];
  for (int j = tid; j < NB; j += 256) h[j] = 0;
  __syncthreads();
  int E = E0 + N;
  int b0 = blockIdx.x * chunk, b1 = min(b0 + chunk, E);
  const int* ep = (const int*)ei;
  for (int e = b0 + tid * 2; e < b1; e += 512) {   // b0,e even (chunk forced even)
    int d0, d1;
    if (e + 1 < E0) {
      if (i64) { int4 v = *(const int4*)(ep + 2 * ((long)E0 + e)); d0 = v.x; d1 = v.z; }
      else     { int2 v = *(const int2*)(ep + (long)E0 + e);       d0 = v.x; d1 = v.y; }
    } else {
      d0 = (e < E0)     ? ldi(ei, (long)E0 + e, i64)     : (e - E0);
      d1 = (e + 1 < E0) ? ldi(ei, (long)E0 + e + 1, i64) : (e + 1 - E0);
    }
    atomicAdd(&h[d0 >> 9], 1);
    if (e + 1 < b1) atomicAdd(&h[d1 >> 9], 1);
  }
  __syncthreads();
  for (int j = tid; j < NB; j += 256)
    brsv[blockIdx.x * NB + j] = atomicAdd(&gcnt[j], h[j]);
}

__global__ void k_bbase(const int* gcnt, int* bbase, int NB) {
  __shared__ int sh[256];
  int tid = threadIdx.x;
  sh[tid] = (tid < NB) ? gcnt[tid] : 0;
  __syncthreads();
  int own = sh[tid];
  for (int ofs = 1; ofs < 256; ofs <<= 1) {
    int v = (tid >= ofs) ? sh[tid - ofs] : 0;
    __syncthreads();
    sh[tid] += v;
    __syncthreads();
  }
  if (tid < NB) bbase[tid] = sh[tid] - own;
  if (tid == NB - 1) bbase[NB] = sh[tid];
}

__global__ void k_bscatter(const void* ei, const int* flags, const int* bbase,
                           const int* brsv, unsigned* pairs, int E0, int N, int NB, int chunk) {
  __shared__ int base_s[256];
  __shared__ int rnk[256];
  int i64 = flags[1], tid = threadIdx.x;
  for (int j = tid; j < NB; j += 256) {
    base_s[j] = bbase[j] + brsv[blockIdx.x * NB + j];
    rnk[j] = 0;
  }
  __syncthreads();
  int E = E0 + N;
  int b0 = blockIdx.x * chunk, b1 = min(b0 + chunk, E);
  const int* ep = (const int*)ei;
  for (int e = b0 + tid * 2; e < b1; e += 512) {
    int s0v, s1v, d0, d1;
    if (e + 1 < E0) {
      if (i64) {
        int4 vs = *(const int4*)(ep + 2 * (long)e);        s0v = vs.x; s1v = vs.z;
        int4 vd = *(const int4*)(ep + 2 * ((long)E0 + e)); d0 = vd.x;  d1 = vd.z;
      } else {
        int2 vs = *(const int2*)(ep + (long)e);            s0v = vs.x; s1v = vs.y;
        int2 vd = *(const int2*)(ep + (long)E0 + e);       d0 = vd.x;  d1 = vd.y;
      }
    } else {
      if (e < E0) { s0v = ldi(ei, e, i64);     d0 = ldi(ei, (long)E0 + e, i64); }
      else        { s0v = e - E0;              d0 = s0v; }
      if (e + 1 < E0) { s1v = ldi(ei, e + 1, i64); d1 = ldi(ei, (long)E0 + e + 1, i64); }
      else            { s1v = e + 1 - E0;          d1 = s1v; }
    }
    {
      int bkt = d0 >> 9;
      int r = atomicAdd(&rnk[bkt], 1);
      pairs[base_s[bkt] + r] = ((unsigned)s0v << 9) | (unsigned)(d0 & 511);
    }
    if (e + 1 < b1) {
      int bkt = d1 >> 9;
      int r = atomicAdd(&rnk[bkt], 1);
      pairs[base_s[bkt] + r] = ((unsigned)s1v << 9) | (unsigned)(d1 & 511);
    }
  }
}

__global__ void k_bsort(const unsigned* pairs, const int* bbase, int* rowp,
                        int* srcs, int N, int NB, int E) {
  __shared__ int h0[512], sc[512], rk[512];
  int b = blockIdx.x, tid = threadIdx.x;
  int s0 = bbase[b], s1 = bbase[b + 1], L = s1 - s0;
  for (int j = tid; j < 512; j += 256) { h0[j] = 0; rk[j] = 0; }
  __syncthreads();
  for (int i = tid; i < L; i += 256) atomicAdd(&h0[pairs[s0 + i] & 511], 1);
  __syncthreads();
  for (int j = tid; j < 512; j += 256) sc[j] = h0[j];
  __syncthreads();
  for (int ofs = 1; ofs < 512; ofs <<= 1) {
    int j0 = tid, j1 = tid + 256;
    int v0 = (j0 >= ofs) ? sc[j0 - ofs] : 0;
    int v1 = (j1 >= ofs) ? sc[j1 - ofs] : 0;
    __syncthreads();
    sc[j0] += v0; sc[j1] += v1;
    __syncthreads();
  }
  for (int j = tid; j < 512; j += 256) {
    int off = sc[j] - h0[j];
    int node = (b << 9) + j;
    if (node < N) rowp[node] = s0 + off;
    sc[j] = off;
  }
  if (b == 0 && tid == 0) rowp[N] = E;
  __syncthreads();
  for (int i = tid; i < L; i += 256) {
    unsigned p = pairs[s0 + i];
    int j = p & 511;
    int r = atomicAdd(&rk[j], 1);
    srcs[s0 + sc[j] + r] = (int)(p >> 9);
  }
}

// ---------------- f32 fallback gemm (per-wave, 4 nodes) ----------------
__device__ __forceinline__ void gemm1_f32(const float* x, const float* params,
                                          unsigned short* h1, float* a_s, float* a_d,
                                          int N, int wave, int lane) {
  int n0 = wave * 4;
  if (n0 >= N) return;
  int nb[4];
#pragma unroll
  for (int j = 0; j < 4; j++) nb[j] = min(n0 + j, N - 1) * 256;
  float acc[4] = {0.f, 0.f, 0.f, 0.f};
  const float* W = params + P_W1;
  for (int k = 0; k < 256; k++) {
    float wv = W[k * 64 + lane];
#pragma unroll
    for (int j = 0; j < 4; j++) acc[j] += x[nb[j] + k] * wv;
  }
  float as1v = params[P_AS1 + lane], ad1v = params[P_AD1 + lane];
#pragma unroll
  for (int j = 0; j < 4; j++) {
    int n = n0 + j;
    if (n >= N) break;
    float hv = acc[j];
    float s = hv * as1v, d = hv * ad1v;
    s += __shfl_xor(s, 1); s += __shfl_xor(s, 2); s += __shfl_xor(s, 4);
    d += __shfl_xor(d, 1); d += __shfl_xor(d, 2); d += __shfl_xor(d, 4);
    h1[(size_t)n * 64 + lane] = f2bfbits(hv);
    if ((lane & 7) == 0) {
      a_s[n * 8 + (lane >> 3)] = s;
      a_d[n * 8 + (lane >> 3)] = d;
    }
  }
}

// ---------------- K1: persistent double-buffered gemm1 (R3 structure, unchanged control) ----------------
__global__ void k_gemm1(const void* x, const unsigned short* w1t, const int* flags,
                        const float* params, unsigned short* h1, float* a_s, float* a_d, int N) {
  __shared__ __align__(16) char smem[32768];
  int tid = threadIdx.x;
  int w = tid >> 6, lane = tid & 63;
  if (flags[0]) {
    int NT = (N + 31) >> 5;
    int l16 = lane & 15, quad = lane >> 4;
    int ch = w * 16 + l16;
    const char* xb = (const char*)x;

    auto stage = [&](int t, int bsel) {
      int row0 = t << 5;
      char* buf = smem + bsel * 16384;
#pragma unroll
      for (int jj = 0; jj < 4; jj++) {
        int g = w * 256 + jj * 64 + lane;
        int r = g >> 5;
        int c = g & 31;
        int gr = row0 + r; if (gr >= N) gr = N - 1;
        const char* src = xb + (size_t)gr * 512 + (size_t)((c << 4) ^ ((r & 7) << 4));
        char* dst = buf + g * 16;
        __builtin_amdgcn_global_load_lds((const __attribute__((address_space(1))) unsigned int*)src,
                                         (__attribute__((address_space(3))) unsigned int*)dst,
                                         16, 0, 0);
      }
    };

    short8 bfr[8];
    const unsigned short* wp = w1t + (size_t)ch * 256 + quad * 8;
#pragma unroll
    for (int i = 0; i < 8; i++) bfr[i] = *(const short8*)(wp + i * 32);
    __builtin_amdgcn_sched_barrier(0);

    int t0 = blockIdx.x;
    if (t0 < NT) stage(t0, 0);
    int cur = 0;
    for (int t = t0; t < NT; t += G1GRID) {
      __syncthreads();
      if (t + G1GRID < NT) stage(t + G1GRID, cur ^ 1);
      int row0 = t << 5;
      const char* buf = smem + cur * 16384;
      floatx4 acc[2];
#pragma unroll
      for (int rg = 0; rg < 2; rg++) {
        floatx4 a4 = {0.f, 0.f, 0.f, 0.f};
        int r = rg * 16 + l16;
        const char* arow = buf + r * 512;
        int swz = (r & 7) << 4;
#pragma unroll
        for (int i = 0; i < 8; i++) {
          short8 afr = *(const short8*)(arow + ((quad * 16 + i * 64) ^ swz));
          a4 = __builtin_amdgcn_mfma_f32_16x16x32_bf16(afr, bfr[i], a4, 0, 0, 0);
        }
        acc[rg] = a4;
      }
      bar_lgkm();
      float* ht = (float*)(smem + cur * 16384);
#pragma unroll
      for (int rg = 0; rg < 2; rg++)
#pragma unroll
        for (int rr = 0; rr < 4; rr++)
          ht[(rg * 16 + quad * 4 + rr) * 67 + ch] = acc[rg][rr];
      bar_lgkm();
      int nl = tid >> 3, head = tid & 7;
      int n = row0 + nl;
      if (n < N) {
        const float* hr = ht + nl * 67 + head * 8;
        float s = 0.f, d = 0.f;
        ushort8v u;
#pragma unroll
        for (int c = 0; c < 8; c++) {
          float v = hr[c];
          s += v * params[P_AS1 + head * 8 + c];
          d += v * params[P_AD1 + head * 8 + c];
          u[c] = f2bfbits(v);
        }
        *(ushort8v*)(h1 + (size_t)n * 64 + head * 8) = u;
        a_s[n * 8 + head] = s;
        a_d[n * 8 + head] = d;
      }
      cur ^= 1;
    }
  } else {
    int NW = (N + 3) >> 2;
    for (int task = blockIdx.x * 4 + w; task < NW; task += G1GRID * 4)
      gemm1_f32((const float*)x, params, h1, a_s, a_d, N, task, lane);
  }
}

// ---------------- K5: layer-1 ONLINE softmax-aggregate + ELU + fused gemm2 (single pass) ----------------
__global__ void k_agg1(const float* params, const unsigned short* h1, const float* a_s,
                       const float* a_d, const int* rowp, const int* srcs,
                       float4* pk, float* ad2, int N) {
  int n = blockIdx.x * (blockDim.x >> 6) + (threadIdx.x >> 6);
  int lane = threadIdx.x & 63;
  if (n >= N) return;
  int start = rowp[n], end = rowp[n + 1];
  int h = lane & 7, es = lane >> 3;
  float adh = a_d[n * 8 + h];
  float m = -1e30f, ssum = 0.f;
  float acc[8] = {0.f,0.f,0.f,0.f,0.f,0.f,0.f,0.f};
  for (int i = start + es; i < end; i += 8) {
    int s = srcs[i];
    float e = a_s[s * 8 + h] + adh;
    e = e > 0.f ? e : 0.2f * e;
    if (e > m) {                       // online rescale (exact; first iter: exp(-inf)=0)
      float sc = __expf(m - e);
      ssum *= sc;
#pragma unroll
      for (int c = 0; c < 8; c++) acc[c] *= sc;
      m = e;
    }
    float ex = __expf(e - m);
    ssum += ex;
    ushort8v u = *(const ushort8v*)(h1 + (size_t)s * 64 + h * 8);  // 16B gather (once!)
#pragma unroll
    for (int c = 0; c < 8; c++) acc[c] += ex * bf2f(u[c]);
  }
  // merge the 8 es-groups with max-rescale
#pragma unroll
  for (int msk = 8; msk <= 32; msk <<= 1) {
    float mo = __shfl_xor(m, msk);
    float so = __shfl_xor(ssum, msk);
    float M = fmaxf(m, mo);
    float scs = __expf(m - M), sco = __expf(mo - M);
    ssum = ssum * scs + so * sco;
#pragma unroll
    for (int c = 0; c < 8; c++) {
      float ao = __shfl_xor(acc[c], msk);
      acc[c] = acc[c] * scs + ao * sco;
    }
    m = M;
  }
  if (es == 0) {   // lanes 0..7, lane == h
    float inv = 1.f / (ssum + 1e-16f);
    float pj0 = 0.f, pj1 = 0.f, pj2 = 0.f;
#pragma unroll
    for (int c = 0; c < 8; c++) {
      float v = acc[c] * inv + params[P_B1 + h * 8 + c];
      v = v > 0.f ? v : (__expf(v) - 1.f);   // ELU
      const float* w2r = params + P_W2 + (h * 8 + c) * 3;
      pj0 += v * w2r[0]; pj1 += v * w2r[1]; pj2 += v * w2r[2];
    }
    pj0 += __shfl_xor(pj0, 1); pj1 += __shfl_xor(pj1, 1); pj2 += __shfl_xor(pj2, 1);
    pj0 += __shfl_xor(pj0, 2); pj1 += __shfl_xor(pj1, 2); pj2 += __shfl_xor(pj2, 2);
    pj0 += __shfl_xor(pj0, 4); pj1 += __shfl_xor(pj1, 4); pj2 += __shfl_xor(pj2, 4);
    if (h == 0) {
      float as2 = pj0*params[P_AS2+0] + pj1*params[P_AS2+1] + pj2*params[P_AS2+2];
      float ad2v = pj0*params[P_AD2+0] + pj1*params[P_AD2+1] + pj2*params[P_AD2+2];
      pk[n] = make_float4(pj0, pj1, pj2, as2);
      ad2[n] = ad2v;
    }
  }
}

// ---------------- K7: layer-2 ONLINE softmax-aggregate + bias -> d_out (single pass) ----------------
__global__ void k_agg2(const float* params, const float4* pk, const float* ad2,
                       const int* rowp, const int* srcs, void* out, const int* flags, int N) {
  int wid = blockIdx.x * (blockDim.x >> 6) + (threadIdx.x >> 6);
  int lane = threadIdx.x & 63;
  int g = lane >> 4, t = lane & 15;
  int n = wid * 4 + g;
  if (n >= N) return;
  int start = rowp[n], end = rowp[n + 1];
  float ad = ad2[n];
  float m = -1e30f, ssum = 0.f, c0 = 0.f, c1 = 0.f, c2 = 0.f;
  for (int i = start + t; i < end; i += 16) {
    float4 v = pk[srcs[i]];              // 16B gather (once!)
    float e = v.w + ad;
    e = e > 0.f ? e : 0.2f * e;
    if (e > m) {
      float sc = __expf(m - e);
      ssum *= sc; c0 *= sc; c1 *= sc; c2 *= sc;
      m = e;
    }
    float ex = __expf(e - m);
    ssum += ex;
    c0 += ex * v.x; c1 += ex * v.y; c2 += ex * v.z;
  }
#pragma unroll
  for (int msk = 1; msk <= 8; msk <<= 1) {
    float mo = __shfl_xor(m, msk);
    float so = __shfl_xor(ssum, msk);
    float a0 = __shfl_xor(c0, msk), a1 = __shfl_xor(c1, msk), a2 = __shfl_xor(c2, msk);
    float M = fmaxf(m, mo);
    float scs = __expf(m - M), sco = __expf(mo - M);
    ssum = ssum * scs + so * sco;
    c0 = c0 * scs + a0 * sco;
    c1 = c1 * scs + a1 * sco;
    c2 = c2 * scs + a2 * sco;
    m = M;
  }
  if (t == 0) {
    float inv = 1.f / (ssum + 1e-16f);
    float o0 = c0 * inv + params[P_B2+0];
    float o1 = c1 * inv + params[P_B2+1];
    float o2 = c2 * inv + params[P_B2+2];
    if (flags[0]) {
      __hip_bfloat16* ob = (__hip_bfloat16*)out;
      ob[n*3+0] = __float2bfloat16(o0);
      ob[n*3+1] = __float2bfloat16(o1);
      ob[n*3+2] = __float2bfloat16(o2);
    } else {
      float* of = (float*)out;
      of[n*3+0] = o0; of[n*3+1] = o1; of[n*3+2] = o2;
    }
  }
}

// ---------------- launch ----------------
extern "C" void kernel_launch(void* const* d_in, const int* in_sizes, int n_in,
                              void* d_out, int out_size, void* d_ws, size_t ws_size,
                              hipStream_t stream) {
  const void* x  = d_in[0];
  const void* ei = d_in[1];
  int N  = in_sizes[0] / 256;   // 100000
  int E0 = in_sizes[1] / 2;     // 3200000
  int E  = E0 + N;
  int NB = (N + 511) >> 9;      // 196 buckets (dst >> 9)
  int chunk = (((E + NBLK_CSR - 1) / NBLK_CSR) + 1) & ~1;   // even: int4/int2 alignment

  char* w = (char*)d_ws;
  size_t off = 0;
  auto alloc = [&](size_t bytes) -> char* {
    char* p = w + off;
    off += (bytes + 255) & ~(size_t)255;
    return p;
  };
  int*            flags  = (int*)           alloc(256);
  float*          params = (float*)         alloc(17408 * 4);
  unsigned short* w1t    = (unsigned short*)alloc(16384 * 2);
  unsigned short* h1     = (unsigned short*)alloc((size_t)N * 64 * 2);
  float*          a_s1   = (float*)         alloc((size_t)N * 8 * 4);
  float*          a_d1   = (float*)         alloc((size_t)N * 8 * 4);
  float4*         pk     = (float4*)        alloc((size_t)N * 16);
  float*          ad2    = (float*)         alloc((size_t)N * 4);
  int*            gcnt   = (int*)           alloc(256 * 4);
  int*            bbase  = (int*)           alloc(257 * 4);
  int*            brsv   = (int*)           alloc((size_t)NBLK_CSR * NB * 4);
  int*            rowp   = (int*)           alloc((size_t)(N + 1) * 4);
  unsigned*       pairs  = (unsigned*)      alloc((size_t)E * 4);
  int*            srcs   = (int*)           alloc((size_t)E * 4);
  (void)ws_size; (void)n_in; (void)out_size;

  hipMemsetAsync(gcnt, 0, 256 * 4, stream);
  k_prep<<<1, 256, 0, stream>>>(x, ei, d_in[2], d_in[3], d_in[4], d_in[5],
                                d_in[6], d_in[7], d_in[8], d_in[9], flags, params, w1t);
  k_gemm1<<<dim3(G1GRID), 256, 0, stream>>>(x, w1t, flags, params, h1, a_s1, a_d1, N);
  k_bcount<<<dim3(NBLK_CSR), 256, 0, stream>>>(ei, flags, gcnt, brsv, E0, N, NB, chunk);
  k_bbase<<<1, 256, 0, stream>>>(gcnt, bbase, NB);
  k_bscatter<<<dim3(NBLK_CSR), 256, 0, stream>>>(ei, flags, bbase, brsv, pairs, E0, N, NB, chunk);
  k_bsort<<<dim3(NB), 256, 0, stream>>>(pairs, bbase, rowp, srcs, N, NB, E);
  k_agg1<<<dim3((N + 3) / 4), 256, 0, stream>>>(params, h1, a_s1, a_d1, rowp, srcs, pk, ad2, N);
  k_agg2<<<dim3((N + 15) / 16), 256, 0, stream>>>(params, pk, ad2, rowp, srcs, d_out, flags, N);
}